// Round 7
// baseline (238.782 us; speedup 1.0000x reference)
//
#include <hip/hip_runtime.h>

typedef __attribute__((ext_vector_type(8))) _Float16 f16x8;
typedef __attribute__((ext_vector_type(4))) float f32x4;
typedef __attribute__((ext_vector_type(2))) float f32x2;

#define MFMA16(A, Bv, Cv) __builtin_amdgcn_mfma_f32_16x16x32_f16(A, Bv, Cv, 0, 0, 0)

#define NB 8
#define CIN 512
#define NC 256
#define NQ 19

// workspace byte offsets
#define WS_WH 0            // 131072 halfs (w_hi, fragment-linear, scaled x32)
#define WS_WL 262144       // 131072 halfs (w_lo)
#define WS_W2T 524288      // 256x256 f32 (w2 transposed)
#define WS_BIAS 786432     // 256 f32
#define WS_M 787456        // 8*19*256 f32

// ---------------- K0: prep (fold BN scale into w, x32 scale, split fp16, w2^T, bias) ------
__global__ __launch_bounds__(256) void k_prep(
    const float* __restrict__ w1, const float* __restrict__ gamma,
    const float* __restrict__ beta, const float* __restrict__ mean,
    const float* __restrict__ var, const float* __restrict__ w2,
    char* __restrict__ ws) {
  _Float16* wh = (_Float16*)(ws + WS_WH);
  _Float16* wl = (_Float16*)(ws + WS_WL);
  float* w2t = (float*)(ws + WS_W2T);
  float* bias = (float*)(ws + WS_BIAS);
  const int bid = blockIdx.x, t = threadIdx.x;
  if (bid < 128) {
    // fragment-linear: elem e = aidx*8 + j, aidx = (kk*16 + mfq)*64 + l
    // lane l holds A[c = mfq*16 + (l&15)][k = kk*32 + (l>>4)*8 + j]
    for (int u = 0; u < 4; ++u) {
      int e = bid * 1024 + u * 256 + t;
      int j = e & 7, l6 = (e >> 3) & 63, mfq = (e >> 9) & 15, kk = e >> 13;
      int c = mfq * 16 + (l6 & 15);
      int k = kk * 32 + (l6 >> 4) * 8 + j;
      float sc = gamma[c] / sqrtf(var[c] + 1e-5f);
      float wf = w1[c * 512 + k] * sc * 32.0f;   // x32 keeps lo-part f16-normal
      _Float16 h = (_Float16)wf;
      wh[e] = h;
      wl[e] = (_Float16)(wf - (float)h);
    }
  } else if (bid < 192) {
    for (int u = 0; u < 4; ++u) {
      int e = (bid - 128) * 1024 + u * 256 + t;
      int i = e >> 8, o = e & 255;
      w2t[e] = w2[o * 256 + i];
    }
  } else {
    float sc = gamma[t] / sqrtf(var[t] + 1e-5f);
    bias[t] = beta[t] - mean[t] * sc;
  }
}

// ---------------- K1: conv1 (split-fp16 MFMA) + BN + ReLU + fused energy partials --------
// BARRIER-FREE K-loop: grid 1024 = 8 b * 128 s-blocks of 128 sigma; 256 thr = 4 waves.
// Wave w = (h = w&1 channel-half, sh = (w>>1) sigma-half): owns 128 ch x 64 sigma.
// B-fragments loaded straight global->reg (per-lane sigma, 8 k-dwords) + in-reg f16 split;
// A-fragments streamed from L2 with distance-2 prefetch. NO LDS, NO barriers until the
// epilogue (per-wave LDS transpose + one __syncthreads for the sigma-half combine).
// LDS: kvq per wave @ w*8448 ([16][132] f32); comb @ 33792 + h*9728 ([19][128] f32).
__global__ __launch_bounds__(256, 2) void k_conv1_energy(
    const float* __restrict__ x, const float* __restrict__ qx,
    const char* __restrict__ ws, float* __restrict__ part) {
  __shared__ __align__(16) char smem[53248];
  const int tid = threadIdx.x;
  const int l = tid & 63, w = tid >> 6;
  const int a = l & 15, g = l >> 4;
  const int h = w & 1;
  const int bid = blockIdx.x;
  const int sblk = bid & 127, b = bid >> 7;
  const int s0 = (sblk << 7) + ((w >> 1) << 6);   // wave sigma base (64 wide)

  const f16x8* __restrict__ whv = (const f16x8*)(ws + WS_WH);
  const f16x8* __restrict__ wlv = (const f16x8*)(ws + WS_WL);

  // per-lane x base: sigma = s0 + nf*16 + a, k = kk*32 + g*8 + j
  const float* __restrict__ xb = x + (((size_t)(b * CIN)) << 14) + s0 + a;

  f32x4 acc[8][4];
  const f32x4 zz = {0.f, 0.f, 0.f, 0.f};
  #pragma unroll
  for (int i = 0; i < 8; ++i)
    #pragma unroll
    for (int j = 0; j < 4; ++j) acc[i][j] = zz;

  float xr[4][8];
  #pragma unroll
  for (int nf = 0; nf < 4; ++nf)
    #pragma unroll
    for (int j = 0; j < 8; ++j)
      xr[nf][j] = xb[((size_t)(g * 8 + j) << 14) + nf * 16];

  f16x8 ah[2], al[2];

  #pragma unroll 1
  for (int kk = 0; kk < 16; ++kk) {
    // A(kk, mf=0,1) issue first (latency covered by the convert below)
    #pragma unroll
    for (int m2 = 0; m2 < 2; ++m2) {
      int aidx = (kk * 16 + h * 8 + m2) * 64 + l;
      ah[m2] = whv[aidx];
      al[m2] = wlv[aidx];
    }
    // convert x(kk) -> split f16 B-fragments (x32 scale keeps lo normal)
    f16x8 bh[4], bl[4];
    #pragma unroll
    for (int nf = 0; nf < 4; ++nf)
      #pragma unroll
      for (int j = 0; j < 8; ++j) {
        float v = xr[nf][j] * 32.f;
        _Float16 hi = (_Float16)v;
        bh[nf][j] = hi;
        bl[nf][j] = (_Float16)(v - (float)hi);
      }
    // prefetch x(kk+1); stays in flight across the whole MFMA phase
    if (kk < 15) {
      #pragma unroll
      for (int nf = 0; nf < 4; ++nf)
        #pragma unroll
        for (int j = 0; j < 8; ++j)
          xr[nf][j] = xb[((size_t)((kk + 1) * 32 + g * 8 + j) << 14) + nf * 16];
    }
    // MFMA: 8 mf x 4 nf x 3; A streamed with distance-2 prefetch
    #pragma unroll
    for (int mf = 0; mf < 8; ++mf) {
      f16x8 cah = ah[mf & 1], cal = al[mf & 1];
      #pragma unroll
      for (int nf = 0; nf < 4; ++nf) {
        acc[mf][nf] = MFMA16(cah, bh[nf], acc[mf][nf]);
        acc[mf][nf] = MFMA16(cal, bh[nf], acc[mf][nf]);
        acc[mf][nf] = MFMA16(cah, bl[nf], acc[mf][nf]);
      }
      if (mf < 6) {
        int aidx = (kk * 16 + h * 8 + mf + 2) * 64 + l;
        ah[mf & 1] = whv[aidx];
        al[mf & 1] = wlv[aidx];
      }
    }
  }

  // undo x32*x32 scaling, add BN bias, ReLU (c = h*128 + mf*16 + g*4 + r4)
  {
    const float* __restrict__ biasg = (const float*)(ws + WS_BIAS);
    #pragma unroll
    for (int mf = 0; mf < 8; ++mf)
      #pragma unroll
      for (int r4 = 0; r4 < 4; ++r4) {
        float bi = biasg[h * 128 + mf * 16 + g * 4 + r4];
        #pragma unroll
        for (int nf = 0; nf < 4; ++nf)
          acc[mf][nf][r4] = fmaxf(acc[mf][nf][r4] * (1.0f / 1024.0f) + bi, 0.f);
      }
  }

  // fused energy: E[n][c] = sum_sigma q[n][sigma]*feat[c][sigma]
  // per-wave LDS transpose (private region, wave-synchronous), all indices static.
  float ea0[19], ea1[19];
  #pragma unroll
  for (int n = 0; n < 19; ++n) { ea0[n] = 0.f; ea1[n] = 0.f; }
  float* kvq = (float*)(smem + w * 8448);          // [16][132] f32
  const float* __restrict__ qb = qx + (((size_t)(b * NQ)) << 14) + s0;

  #pragma unroll
  for (int nf = 0; nf < 4; ++nf) {
    #pragma unroll
    for (int mf = 0; mf < 8; ++mf)
      *(f32x4*)&kvq[a * 132 + mf * 16 + g * 4] = acc[mf][nf];
    asm volatile("s_waitcnt lgkmcnt(0)" ::: "memory");
    __builtin_amdgcn_sched_barrier(0);
    #pragma unroll
    for (int spc = 0; spc < 4; ++spc) {
      float4 qv[19];
      #pragma unroll
      for (int n = 0; n < 19; ++n)
        qv[n] = *(const float4*)(qb + ((size_t)n << 14) + nf * 16 + spc * 4);
      #pragma unroll
      for (int sj = 0; sj < 4; ++sj) {
        float kv0 = kvq[(spc * 4 + sj) * 132 + l];
        float kv1 = kvq[(spc * 4 + sj) * 132 + 64 + l];
        #pragma unroll
        for (int n = 0; n < 19; ++n) {
          float qs = ((const float*)&qv[n])[sj];
          ea0[n] = fmaf(qs, kv0, ea0[n]);
          ea1[n] = fmaf(qs, kv1, ea1[n]);
        }
      }
    }
  }

  // sigma-half combine: waves (h, sh=1) publish; waves (h, sh=0) reduce + write partials
  float* comb = (float*)(smem + 33792 + h * 9728);  // [19][128] f32
  if (w >= 2) {
    #pragma unroll
    for (int n = 0; n < 19; ++n) {
      comb[n * 128 + l] = ea0[n];
      comb[n * 128 + 64 + l] = ea1[n];
    }
  }
  __syncthreads();
  if (w < 2) {
    float* pp = part + (size_t)bid * (NQ * 256) + h * 128 + l;
    #pragma unroll
    for (int n = 0; n < 19; ++n) {
      pp[n * 256]      = ea0[n] + comb[n * 128 + l];
      pp[n * 256 + 64] = ea1[n] + comb[n * 128 + 64 + l];
    }
  }
}

// ---------------- K2: reduce partials + softmax over c + M = attn @ w2^T ------------------
__global__ __launch_bounds__(256) void k_softmax_m(
    const float* __restrict__ part, const char* __restrict__ ws,
    float* __restrict__ Mout) {
  const int bn = blockIdx.x;
  const int b = bn / 19, n = bn % 19;
  const int t = threadIdx.x;
  const float* __restrict__ w2t = (const float*)(ws + WS_W2T);
  float e = 0.f;
  const float* pp = part + ((size_t)(b * 128) * NQ + n) * 256 + t;
  for (int sb = 0; sb < 128; ++sb)
    e += pp[(size_t)sb * (NQ * 256)];
  __shared__ float sred[4];
  __shared__ float attn_lds[256];
  float m = e;
  #pragma unroll
  for (int d = 1; d < 64; d <<= 1) m = fmaxf(m, __shfl_xor(m, d, 64));
  if ((t & 63) == 0) sred[t >> 6] = m;
  __syncthreads();
  m = fmaxf(fmaxf(sred[0], sred[1]), fmaxf(sred[2], sred[3]));
  float p = __expf(e - m);
  float s = p;
  #pragma unroll
  for (int d = 1; d < 64; d <<= 1) s += __shfl_xor(s, d, 64);
  __syncthreads();
  if ((t & 63) == 0) sred[t >> 6] = s;
  __syncthreads();
  s = sred[0] + sred[1] + sred[2] + sred[3];
  attn_lds[t] = p / s;
  __syncthreads();
  float macc = 0.f;
  #pragma unroll 8
  for (int i = 0; i < 256; ++i)
    macc = fmaf(attn_lds[i], w2t[i * 256 + t], macc);
  Mout[(size_t)bn * 256 + t] = macc;
}

// ---------------- K3: out[b,o,s] = sum_n M[b,n,o]*q[b,n,s] + b2[o] ------------------------
__global__ __launch_bounds__(256, 2) void k_out(
    const float* __restrict__ qx, const float* __restrict__ Mg,
    const float* __restrict__ b2, float* __restrict__ out) {
  const int bid = blockIdx.x;
  const int b = bid >> 6, sc = bid & 63;
  const int s0 = sc * 256;
  const int t = threadIdx.x;
  __shared__ float qlds[19 * 256];
  for (int idx = t; idx < 19 * 256; idx += 256) {
    int n = idx >> 8, s = idx & 255;
    qlds[idx] = qx[((size_t)(b * NQ + n) << 14) + s0 + s];
  }
  __syncthreads();
  const int tg = t >> 4, a2 = (t & 15) * 2;
  #pragma unroll 1
  for (int ocg = 0; ocg < 4; ++ocg) {
    float m[4][19];
    float bi[4];
    #pragma unroll
    for (int oj = 0; oj < 4; ++oj) {
      int o = (ocg * 4 + oj) * 16 + tg;
      bi[oj] = b2[o];
      #pragma unroll
      for (int n = 0; n < 19; ++n)
        m[oj][n] = Mg[((size_t)b * NQ + n) * 256 + o];
    }
    #pragma unroll 1
    for (int sp = 0; sp < 8; ++sp) {
      int s = sp * 32 + a2;
      f32x2 acc2[4];
      #pragma unroll
      for (int oj = 0; oj < 4; ++oj) { acc2[oj].x = bi[oj]; acc2[oj].y = bi[oj]; }
      #pragma unroll
      for (int n = 0; n < 19; ++n) {
        f32x2 q2 = *(const f32x2*)&qlds[n * 256 + s];
        #pragma unroll
        for (int oj = 0; oj < 4; ++oj) {
          acc2[oj].x = fmaf(m[oj][n], q2.x, acc2[oj].x);
          acc2[oj].y = fmaf(m[oj][n], q2.y, acc2[oj].y);
        }
      }
      #pragma unroll
      for (int oj = 0; oj < 4; ++oj) {
        int o = (ocg * 4 + oj) * 16 + tg;
        *(f32x2*)&out[((size_t)(b * NC + o) << 14) + s0 + s] = acc2[oj];
      }
    }
  }
}

extern "C" void kernel_launch(void* const* d_in, const int* in_sizes, int n_in,
                              void* d_out, int out_size, void* d_ws, size_t ws_size,
                              hipStream_t stream) {
  const float* x     = (const float*)d_in[0];
  const float* cx    = (const float*)d_in[1];
  const float* w1    = (const float*)d_in[2];
  const float* gamma = (const float*)d_in[3];
  const float* beta  = (const float*)d_in[4];
  const float* mean  = (const float*)d_in[5];
  const float* var   = (const float*)d_in[6];
  const float* w2    = (const float*)d_in[7];
  const float* b2    = (const float*)d_in[8];
  char* ws = (char*)d_ws;
  float* out = (float*)d_out;
  // energy partials [1024 tiles][19][256] f32 (~20 MB) overlay d_out; consumed by
  // k_softmax_m before k_out overwrites the full output. Deterministic.
  float* part = (float*)d_out;
  float* Mptr = (float*)(ws + WS_M);

  k_prep<<<193, 256, 0, stream>>>(w1, gamma, beta, mean, var, w2, ws);
  k_conv1_energy<<<1024, 256, 0, stream>>>(x, cx, ws, part);
  k_softmax_m<<<152, 256, 0, stream>>>(part, ws, Mptr);
  k_out<<<512, 256, 0, stream>>>(cx, Mptr, b2, out);
}